// Round 5
// baseline (256.056 us; speedup 1.0000x reference)
//
#include <hip/hip_runtime.h>
#include <hip/hip_bf16.h>
#include <stdint.h>

typedef __bf16 bf16;
typedef bf16 bf16x8 __attribute__((ext_vector_type(8)));
typedef float f32x4 __attribute__((ext_vector_type(4)));

#define LOGSQRT2PI 0.9189385332046727f

__device__ __forceinline__ void gload_lds16(const void* g, void* l) {
    __builtin_amdgcn_global_load_lds((__attribute__((address_space(1))) void*)g,
                                     (__attribute__((address_space(3))) void*)l,
                                     16, 0, 0);
}

// ---- zero d_out (y region + the two scalar accumulators) ----
__global__ void k_zero(float* p, int n) {
    int stride = gridDim.x * blockDim.x;
    for (int i = blockIdx.x * blockDim.x + threadIdx.x; i < n; i += stride) p[i] = 0.f;
}

// ---- weight prep: W = mu + (1e-6+softplus(p))*eps ; write Wt[n][k] bf16 ;
// ---- accumulate lqw/lpw ----
__global__ void k_prep(const float* __restrict__ mu, const float* __restrict__ p,
                       const float* __restrict__ eps, bf16* __restrict__ Wt,
                       int K, int N, int Npad, float* __restrict__ osc) {
    int total = K * Npad;
    float lqw = 0.0f, lpw = 0.0f;
    for (int idx = blockIdx.x * blockDim.x + threadIdx.x; idx < total;
         idx += gridDim.x * blockDim.x) {
        int k = idx / Npad;
        int n = idx - k * Npad;
        float w = 0.0f;
        if (n < N) {
            int src = k * N + n;
            float m = mu[src];
            float e = eps[src];
            float sd = 1e-6f + log1pf(expf(p[src]));
            w = m + sd * e;
            float z = (w - m) / sd;
            lqw += -LOGSQRT2PI - logf(sd) - 0.5f * z * z;
            lpw += -LOGSQRT2PI - 0.5f * w * w;
        }
        Wt[n * K + k] = (bf16)w;
    }
    #pragma unroll
    for (int off = 32; off; off >>= 1) {
        lqw += __shfl_down(lqw, off);
        lpw += __shfl_down(lpw, off);
    }
    if ((threadIdx.x & 63) == 0) {
        atomicAdd(&osc[0], lqw);
        atomicAdd(&osc[1], lpw);
    }
}

// ============================================================================
// B-stationary BARRIER-FREE GEMM.  Block = 8 waves (512 thr), one 64-col
// B-slice resident in LDS (64 KB, fragment-ordered: chunk(jg,ks) = 1 KB at
// (jg*16+ks)*512, lane l: B[cb+jg*16+(l&15)][ks*32+(l>>4)*8..+8] at +l*8).
// After ONE fill barrier, every wave runs free: 32-row tile, A streamed
// global->reg (depth 2/3 rotation, static idx), 8 MFMA per K=32 step.
// 2 blocks/CU (80 KB LDS), 4 waves/SIMD -> TLP hides load latency without
// any lockstep.  Grid 512 persistent; 4 M-tiles/block.
// XCD grouping: xcd = bid&7; per xcd: 8 bn-slices x 8 mslots concurrent ->
// the 8 readers of any A-line share one XCD's L2.
//
// LAYER 1: A = x fp32 (in-reg cvt; kills the k_cvt pass), out: h1 in
//   fragment-chunk order (chunk (RG*16+ks_g)*512 + l*8) via wave-private
//   LDS transpose (2 KB scratch/wave, no barriers).
// LAYER 2: A = h1 chunks (1 KB/wave contiguous loads), out: fused layer-3
//   partial y via same transpose + 2 MFMA vs W3t + atomicAdd.
// Transpose scratch swizzle: elem (row16, col) at row16*64 +
//   ((col>>3)^(row16&7))*8 + (col&7); b128 read side <=2-way conflicts.
// ============================================================================
template<int LAYER>
__global__ __launch_bounds__(512, 4)
void k_bgemm(const float* __restrict__ X, const bf16* __restrict__ Ac,
             const bf16* __restrict__ Wt, bf16* __restrict__ H,
             const bf16* __restrict__ W3t, float* __restrict__ Y) {
    __shared__ __align__(16) bf16 LDSb[32768 + 8192];   // 64 KB B + 16 KB scratch
    const int tid = threadIdx.x;
    const int l = tid & 63, w = tid >> 6;
    const int l8 = l * 8;
    const int xcd   = blockIdx.x & 7;
    const int slot  = blockIdx.x >> 3;    // 0..63
    const int bn    = slot & 7;
    const int mslot = slot >> 3;          // 0..7
    const int cb    = bn * 64;

    // ---- one-time B fill (wave w covers chunks w, w+8, ..) ----
    #pragma unroll
    for (int i = 0; i < 8; i++) {
        int c = i * 8 + w;
        int jg = c >> 4, ks = c & 15;
        gload_lds16(Wt + (cb + jg * 16 + (l & 15)) * 512 + ks * 32 + (l >> 4) * 8,
                    &LDSb[c * 512 + l8]);
    }
    bf16x8 b3[2];
    if (LAYER == 2) {
        b3[0] = *(const bf16x8*)(W3t + (l & 15) * 512 + cb + (l >> 4) * 8);
        b3[1] = *(const bf16x8*)(W3t + (l & 15) * 512 + cb + 32 + (l >> 4) * 8);
    }
    asm volatile("s_waitcnt vmcnt(0)" ::: "memory");
    __builtin_amdgcn_s_barrier();        // the only barrier in the kernel

    bf16* scr = &LDSb[32768 + w * 1024]; // wave-private 16x64 bf16 (2 KB)

    for (int t = 0; t < 4; ++t) {
        const long mt  = (long)((xcd * 8 + mslot) * 4 + t);   // 0..255
        const long m0w = mt * 256 + w * 32;
        const long RG0 = m0w >> 4;

        f32x4 acc[2][4];
        #pragma unroll
        for (int i = 0; i < 2; i++)
            #pragma unroll
            for (int j = 0; j < 4; j++) acc[i][j] = (f32x4){0.f, 0.f, 0.f, 0.f};
        bf16x8 bfr[4];

        if (LAYER == 1) {
            const float* xr0 = X + (m0w + (l & 15)) * 512 + ((l >> 4) * 8);
            const float* xr1 = xr0 + 16 * 512;
            float4 ap[2][4];              // depth-2 rotation, static indices
            #pragma unroll
            for (int s = 0; s < 2; s++) {
                ap[s][0] = *(const float4*)(xr0 + s * 32);
                ap[s][1] = *(const float4*)(xr0 + s * 32 + 4);
                ap[s][2] = *(const float4*)(xr1 + s * 32);
                ap[s][3] = *(const float4*)(xr1 + s * 32 + 4);
            }
            #pragma unroll
            for (int ks = 0; ks < 16; ks++) {
                const int s = ks & 1;
                bf16x8 a0, a1;
                #pragma unroll
                for (int e = 0; e < 4; e++) {
                    a0[e] = (bf16)ap[s][0][e]; a0[e + 4] = (bf16)ap[s][1][e];
                    a1[e] = (bf16)ap[s][2][e]; a1[e + 4] = (bf16)ap[s][3][e];
                }
                if (ks < 14) {
                    ap[s][0] = *(const float4*)(xr0 + (ks + 2) * 32);
                    ap[s][1] = *(const float4*)(xr0 + (ks + 2) * 32 + 4);
                    ap[s][2] = *(const float4*)(xr1 + (ks + 2) * 32);
                    ap[s][3] = *(const float4*)(xr1 + (ks + 2) * 32 + 4);
                }
                #pragma unroll
                for (int j = 0; j < 4; j++)
                    bfr[j] = *(const bf16x8*)&LDSb[(j * 16 + ks) * 512 + l8];
                #pragma unroll
                for (int j = 0; j < 4; j++) {
                    acc[0][j] = __builtin_amdgcn_mfma_f32_16x16x32_bf16(a0, bfr[j], acc[0][j], 0, 0, 0);
                    acc[1][j] = __builtin_amdgcn_mfma_f32_16x16x32_bf16(a1, bfr[j], acc[1][j], 0, 0, 0);
                }
            }
        } else {
            const bf16* ar0 = Ac + RG0 * 8192 + l8;        // chunk (RG0*16+ks)*512
            const bf16* ar1 = ar0 + 8192;
            bf16x8 ap[3][2];              // depth-3 rotation
            #pragma unroll
            for (int s = 0; s < 3; s++) {
                ap[s][0] = *(const bf16x8*)(ar0 + s * 512);
                ap[s][1] = *(const bf16x8*)(ar1 + s * 512);
            }
            #pragma unroll
            for (int ks = 0; ks < 16; ks++) {
                const int s = ks % 3;
                bf16x8 a0 = ap[s][0], a1 = ap[s][1];
                if (ks < 13) {
                    ap[s][0] = *(const bf16x8*)(ar0 + (ks + 3) * 512);
                    ap[s][1] = *(const bf16x8*)(ar1 + (ks + 3) * 512);
                }
                #pragma unroll
                for (int j = 0; j < 4; j++)
                    bfr[j] = *(const bf16x8*)&LDSb[(j * 16 + ks) * 512 + l8];
                #pragma unroll
                for (int j = 0; j < 4; j++) {
                    acc[0][j] = __builtin_amdgcn_mfma_f32_16x16x32_bf16(a0, bfr[j], acc[0][j], 0, 0, 0);
                    acc[1][j] = __builtin_amdgcn_mfma_f32_16x16x32_bf16(a1, bfr[j], acc[1][j], 0, 0, 0);
                }
            }
        }

        // ---- epilogue: wave-private transpose to MFMA-A fragment order ----
        f32x4 yacc[2];
        if (LAYER == 2) {
            yacc[0] = (f32x4){0.f, 0.f, 0.f, 0.f};
            yacc[1] = (f32x4){0.f, 0.f, 0.f, 0.f};
        }
        #pragma unroll
        for (int rg = 0; rg < 2; rg++) {
            #pragma unroll
            for (int j = 0; j < 4; j++)
                #pragma unroll
                for (int q = 0; q < 4; q++) {
                    int row16 = (l >> 4) * 4 + q;
                    int col   = j * 16 + (l & 15);
                    float v = fmaxf(acc[rg][j][q], 0.f);   // ReLU (both layers)
                    scr[row16 * 64 + (((col >> 3) ^ (row16 & 7)) * 8) + (col & 7)] = (bf16)v;
                }
            asm volatile("s_waitcnt lgkmcnt(0)" ::: "memory");
            #pragma unroll
            for (int kk = 0; kk < 2; kk++) {
                int row = l & 15;
                int cc  = kk * 4 + (l >> 4);
                bf16x8 a3 = *(const bf16x8*)&scr[row * 64 + ((cc ^ (row & 7)) * 8)];
                if (LAYER == 1) {
                    *(bf16x8*)(H + ((RG0 + rg) * 16 + (bn * 2 + kk)) * 512 + l8) = a3;
                } else {
                    yacc[rg] = __builtin_amdgcn_mfma_f32_16x16x32_bf16(a3, b3[kk], yacc[rg], 0, 0, 0);
                }
            }
            asm volatile("s_waitcnt lgkmcnt(0)" ::: "memory");
        }
        if (LAYER == 2) {
            if ((l & 15) < 10) {
                #pragma unroll
                for (int rg = 0; rg < 2; rg++)
                    #pragma unroll
                    for (int q = 0; q < 4; q++) {
                        long row = m0w + rg * 16 + (l >> 4) * 4 + q;
                        atomicAdd(Y + row * 10 + (l & 15), yacc[rg][q]);
                    }
            }
        }
    }
}

extern "C" void kernel_launch(void* const* d_in, const int* in_sizes, int n_in,
                              void* d_out, int out_size, void* d_ws, size_t ws_size,
                              hipStream_t stream) {
    const float* x   = (const float*)d_in[0];
    const float* mu1 = (const float*)d_in[1];
    const float* p1  = (const float*)d_in[2];
    const float* e1  = (const float*)d_in[3];
    const float* mu2 = (const float*)d_in[4];
    const float* p2  = (const float*)d_in[5];
    const float* e2  = (const float*)d_in[6];
    const float* mu3 = (const float*)d_in[7];
    const float* p3  = (const float*)d_in[8];
    const float* e3  = (const float*)d_in[9];
    float* out = (float*)d_out;

    const int B = 65536, D = 512, DO = 10, DOP = 16;

    char* ws = (char*)d_ws;
    bf16* Wt1 = (bf16*)(ws);
    bf16* Wt2 = (bf16*)(ws + 524288);
    bf16* Wt3 = (bf16*)(ws + 1048576);
    bf16* h1c = (bf16*)(ws + 1114112);   // h1 in fragment-chunk order, 64 MB

    float* osc = out + (long)B * DO;

    hipLaunchKernelGGL(k_zero, dim3(512), dim3(256), 0, stream, out, out_size);
    hipLaunchKernelGGL(k_prep, dim3(256), dim3(256), 0, stream, mu1, p1, e1, Wt1, D, D,  D,   osc);
    hipLaunchKernelGGL(k_prep, dim3(256), dim3(256), 0, stream, mu2, p2, e2, Wt2, D, D,  D,   osc);
    hipLaunchKernelGGL(k_prep, dim3(16),  dim3(256), 0, stream, mu3, p3, e3, Wt3, D, DO, DOP, osc);
    hipLaunchKernelGGL((k_bgemm<1>), dim3(512), dim3(512), 0, stream,
                       x, (const bf16*)nullptr, Wt1, h1c, (const bf16*)nullptr, (float*)nullptr);
    hipLaunchKernelGGL((k_bgemm<2>), dim3(512), dim3(512), 0, stream,
                       (const float*)nullptr, h1c, Wt2, (bf16*)nullptr, Wt3, out);
}

// Round 6
// 196.687 us; speedup vs baseline: 1.3018x; 1.3018x over previous
//
#include <hip/hip_runtime.h>
#include <hip/hip_bf16.h>
#include <stdint.h>

typedef __bf16 bf16;
typedef bf16 bf16x4 __attribute__((ext_vector_type(4)));
typedef bf16 bf16x8 __attribute__((ext_vector_type(8)));
typedef float f32x4 __attribute__((ext_vector_type(4)));

#define LOGSQRT2PI 0.9189385332046727f

__device__ __forceinline__ void gload_lds16(const void* g, void* l) {
    __builtin_amdgcn_global_load_lds((__attribute__((address_space(1))) void*)g,
                                     (__attribute__((address_space(3))) void*)l,
                                     16, 0, 0);
}

// ---- zero d_out (y region + the two scalar accumulators) ----
__global__ void k_zero(float* p, int n) {
    int stride = gridDim.x * blockDim.x;
    for (int i = blockIdx.x * blockDim.x + threadIdx.x; i < n; i += stride) p[i] = 0.f;
}

// ---- merged weight prep: W = mu + (1e-6+softplus(p))*eps ; Wt[n][k] bf16 ;
// ---- lqw/lpw atomics.  One launch: blocks 0-255 W1, 256-511 W2, 512-527 W3.
__device__ __forceinline__ void prep_body(const float* __restrict__ mu,
        const float* __restrict__ p, const float* __restrict__ eps,
        bf16* __restrict__ Wt, int N, int Npad, float* __restrict__ osc,
        int vb, int nblocks) {
    int total = 512 * Npad;
    float lqw = 0.f, lpw = 0.f;
    for (int idx = vb * 256 + threadIdx.x; idx < total; idx += nblocks * 256) {
        int k = idx / Npad, n = idx - k * Npad;
        float w = 0.f;
        if (n < N) {
            int src = k * N + n;
            float m = mu[src], e = eps[src];
            float sd = 1e-6f + log1pf(expf(p[src]));
            w = m + sd * e;
            float z = (w - m) / sd;
            lqw += -LOGSQRT2PI - logf(sd) - 0.5f * z * z;
            lpw += -LOGSQRT2PI - 0.5f * w * w;
        }
        Wt[n * 512 + k] = (bf16)w;
    }
    #pragma unroll
    for (int off = 32; off; off >>= 1) {
        lqw += __shfl_down(lqw, off);
        lpw += __shfl_down(lpw, off);
    }
    if ((threadIdx.x & 63) == 0) {
        atomicAdd(&osc[0], lqw);
        atomicAdd(&osc[1], lpw);
    }
}

__global__ void k_prep_all(const float* __restrict__ mu1, const float* __restrict__ p1,
                           const float* __restrict__ e1,
                           const float* __restrict__ mu2, const float* __restrict__ p2,
                           const float* __restrict__ e2,
                           const float* __restrict__ mu3, const float* __restrict__ p3,
                           const float* __restrict__ e3,
                           bf16* __restrict__ Wt1, bf16* __restrict__ Wt2,
                           bf16* __restrict__ Wt3, float* __restrict__ osc) {
    int b = blockIdx.x;
    if (b < 256)      prep_body(mu1, p1, e1, Wt1, 512, 512, osc, b, 256);
    else if (b < 512) prep_body(mu2, p2, e2, Wt2, 512, 512, osc, b - 256, 256);
    else              prep_body(mu3, p3, e3, Wt3, 10,  16,  osc, b - 512, 16);
}

// ---- x fp32 -> bf16 (row-major, coalesced) ----
__global__ void k_cvt(const float4* __restrict__ in, bf16x4* __restrict__ out, int n4) {
    int stride = gridDim.x * blockDim.x;
    for (int i = blockIdx.x * blockDim.x + threadIdx.x; i < n4; i += stride) {
        float4 v = in[i];
        bf16x4 o;
        o[0] = (bf16)v.x; o[1] = (bf16)v.y; o[2] = (bf16)v.z; o[3] = (bf16)v.w;
        out[i] = o;
    }
}

// ============================================================================
// 256x256 main loop (round-3 k_l23 structure — best measured ≈48 µs):
//   8 waves (2M x 4N), BK=64 (2 ks-halves of 32), double-buffered LDS,
//   global_load_lds staging both operands, fragment-ordered 1KB chunks
//   (conflict-free ds_read_b128), counted vmcnt(8) gates.
// k_g1: epilogue = b128 LDS-bounce C-write (h1, ReLU).
// k_g2: epilogue = fused layer-3 partial (h2 stays in LDS; y atomics).
// ============================================================================

#define MFMA16(IH) {                                                           \
    _Pragma("unroll")                                                          \
    for (int i = 0; i < 4; i++)                                                \
        _Pragma("unroll")                                                      \
        for (int j = 0; j < 4; j++)                                            \
            acc[(IH) * 4 + i][j] = __builtin_amdgcn_mfma_f32_16x16x32_bf16(    \
                afr[i], bfr[j], acc[(IH) * 4 + i][j], 0, 0, 0); }

#define LOADA(IH, KS) { _Pragma("unroll")                                      \
    for (int i = 0; i < 4; i++)                                                \
        afr[i] = *(const bf16x8*)&LDSe[buf * 16384 +                           \
                 ((wm * 8 + (IH) * 4 + i) * 2 + (KS)) * 512 + l8]; }
#define LOADB(KS) { _Pragma("unroll")                                          \
    for (int j = 0; j < 4; j++)                                                \
        bfr[j] = *(const bf16x8*)&LDSe[32768 + buf * 16384 +                   \
                 ((wn * 4 + j) * 2 + (KS)) * 512 + l8]; }

#define GEMM_PROLOGUE_AND_LOOP()                                               \
    const int tid = threadIdx.x;                                               \
    const int l = tid & 63;                                                    \
    const int w = tid >> 6;                                                    \
    const int wm = w >> 2, wn = w & 3;                                         \
    const int l8 = l * 8;                                                      \
    const int bid = blockIdx.x;                                                \
    const int logical = (bid & 7) * 64 + (bid >> 3);                           \
    const long bm = (long)(logical >> 1) * 256;                                \
    const int  bn = (logical & 1) * 256;                                       \
    const bf16* Asrc = A  + (bm + w * 16 + (l & 15)) * 512 + ((l >> 4) * 8);   \
    const bf16* Bsrc = Bt + ((long)bn + w * 16 + (l & 15)) * 512 + ((l >> 4) * 8); \
    f32x4 acc[8][4];                                                           \
    _Pragma("unroll")                                                          \
    for (int i = 0; i < 8; i++)                                                \
        _Pragma("unroll")                                                      \
        for (int j = 0; j < 4; j++) acc[i][j] = (f32x4){0.f, 0.f, 0.f, 0.f};   \
    bf16x8 afr[4], bfr[4];                                                     \
    ASTG(0, 0, 0); BSTG(0, 0, 0);                                              \
    ASTG(0, 1, 0); BSTG(0, 1, 0);                                              \
    ASTG(1, 0, 1); BSTG(1, 0, 1);                                              \
    asm volatile("s_waitcnt vmcnt(4)" ::: "memory");                           \
    __builtin_amdgcn_s_barrier();                                              \
    for (int T = 0; T < 8; ++T) {                                              \
        const int buf = T & 1, nb = buf ^ 1;                                   \
        LOADB(0); LOADA(0, 0);                                                 \
        if (T < 7) ASTG(T + 1, 1, nb);                                         \
        __builtin_amdgcn_s_barrier();                                          \
        __builtin_amdgcn_s_setprio(1); MFMA16(0); __builtin_amdgcn_s_setprio(0); \
        __builtin_amdgcn_s_barrier();                                          \
        LOADA(1, 0);                                                           \
        if (T < 7) BSTG(T + 1, 1, nb);                                         \
        __builtin_amdgcn_s_barrier();                                          \
        __builtin_amdgcn_s_setprio(1); MFMA16(1); __builtin_amdgcn_s_setprio(0); \
        if (T < 7) { asm volatile("s_waitcnt vmcnt(8)" ::: "memory"); }        \
        else       { asm volatile("s_waitcnt vmcnt(0)" ::: "memory"); }        \
        __builtin_amdgcn_s_barrier();                                          \
        LOADB(1); LOADA(0, 1);                                                 \
        if (T < 6) ASTG(T + 2, 0, buf);                                        \
        __builtin_amdgcn_s_barrier();                                          \
        __builtin_amdgcn_s_setprio(1); MFMA16(0); __builtin_amdgcn_s_setprio(0); \
        __builtin_amdgcn_s_barrier();                                          \
        LOADA(1, 1);                                                           \
        if (T < 6) BSTG(T + 2, 0, buf);                                        \
        __builtin_amdgcn_s_barrier();                                          \
        __builtin_amdgcn_s_setprio(1); MFMA16(1); __builtin_amdgcn_s_setprio(0); \
        if (T < 6)       { asm volatile("s_waitcnt vmcnt(8)" ::: "memory"); }  \
        else if (T == 6) { asm volatile("s_waitcnt vmcnt(4)" ::: "memory"); }  \
        __builtin_amdgcn_s_barrier();                                          \
    }

#define ASTG(TT, KS, BUF) do {                                                 \
    gload_lds16(Asrc + (TT) * 64 + (KS) * 32,                                  \
                &LDSe[(BUF) * 16384 + ((w) * 2 + (KS)) * 512 + l8]);           \
    gload_lds16(Asrc + 65536 + (TT) * 64 + (KS) * 32,                          \
                &LDSe[(BUF) * 16384 + ((8 + w) * 2 + (KS)) * 512 + l8]);       \
} while (0)
#define BSTG(TT, KS, BUF) do {                                                 \
    gload_lds16(Bsrc + (TT) * 64 + (KS) * 32,                                  \
                &LDSe[32768 + (BUF) * 16384 + ((w) * 2 + (KS)) * 512 + l8]);   \
    gload_lds16(Bsrc + 65536 + (TT) * 64 + (KS) * 32,                          \
                &LDSe[32768 + (BUF) * 16384 + ((8 + w) * 2 + (KS)) * 512 + l8]); \
} while (0)

// ---- Layer 1: h1 = relu(xb @ W1t), C written via b128 LDS bounce ----
__global__ __launch_bounds__(512, 2)
void k_g1(const bf16* __restrict__ A, const bf16* __restrict__ Bt,
          bf16* __restrict__ C) {
    __shared__ __align__(16) bf16 LDSe[65536];   // 128 KB
    GEMM_PROLOGUE_AND_LOOP()

    // epilogue: acc -> LDS bf16 [256][256] (ReLU, 16B-chunk swizzle
    // phys_chunk = cc ^ (row&7)) -> coalesced dwordx4 global stores
    #pragma unroll
    for (int ih = 0; ih < 8; ih++)
        #pragma unroll
        for (int j = 0; j < 4; j++)
            #pragma unroll
            for (int q = 0; q < 4; q++) {
                int row = wm * 128 + ih * 16 + (l >> 4) * 4 + q;
                int col = wn * 64 + j * 16 + (l & 15);
                float v = fmaxf(acc[ih][j][q], 0.f);
                LDSe[row * 256 + ((col >> 3) ^ (row & 7)) * 8 + (col & 7)] = (bf16)v;
            }
    asm volatile("s_waitcnt lgkmcnt(0)" ::: "memory");
    __builtin_amdgcn_s_barrier();
    #pragma unroll
    for (int i = 0; i < 16; i++) {
        int row = i * 16 + (tid >> 5);
        int cc = tid & 31;
        bf16x8 v = *(const bf16x8*)&LDSe[row * 256 + ((cc ^ (row & 7)) * 8)];
        *(bf16x8*)(C + (bm + row) * 512 + bn + cc * 8) = v;
    }
}

// ---- Layers 2+3: h2 = relu(h1 @ W2t) kept in LDS; y += h2_slice @ W3t ----
__global__ __launch_bounds__(512, 2)
void k_g2(const bf16* __restrict__ A, const bf16* __restrict__ Bt,
          const bf16* __restrict__ W3t, float* __restrict__ Y) {
    __shared__ __align__(16) bf16 LDSe[65536];
    GEMM_PROLOGUE_AND_LOOP()

    // h2 tile -> LDS (ReLU, swizzled)
    #pragma unroll
    for (int ih = 0; ih < 8; ih++)
        #pragma unroll
        for (int j = 0; j < 4; j++)
            #pragma unroll
            for (int q = 0; q < 4; q++) {
                int row = wm * 128 + ih * 16 + (l >> 4) * 4 + q;
                int col = wn * 64 + j * 16 + (l & 15);
                float v = fmaxf(acc[ih][j][q], 0.f);
                LDSe[row * 256 + ((col >> 3) ^ (row & 7)) * 8 + (col & 7)] = (bf16)v;
            }
    asm volatile("s_waitcnt lgkmcnt(0)" ::: "memory");
    __builtin_amdgcn_s_barrier();

    // layer 3 partial: y[rows][0..9] += h2[rows][bn..bn+255] @ W3t[0..15][bn..]
    bf16x8 b3[8];
    #pragma unroll
    for (int ks = 0; ks < 8; ks++)
        b3[ks] = *(const bf16x8*)(W3t + (l & 15) * 512 + bn + ks * 32 + (l >> 4) * 8);
    f32x4 yacc[2];
    yacc[0] = (f32x4){0.f, 0.f, 0.f, 0.f};
    yacc[1] = (f32x4){0.f, 0.f, 0.f, 0.f};
    #pragma unroll
    for (int fr = 0; fr < 2; fr++)
        #pragma unroll
        for (int ks = 0; ks < 8; ks++) {
            int row = w * 32 + fr * 16 + (l & 15);
            int cc = ks * 4 + (l >> 4);
            bf16x8 a3 = *(const bf16x8*)&LDSe[row * 256 + ((cc ^ (row & 7)) * 8)];
            yacc[fr] = __builtin_amdgcn_mfma_f32_16x16x32_bf16(a3, b3[ks], yacc[fr], 0, 0, 0);
        }
    if ((l & 15) < 10) {
        #pragma unroll
        for (int fr = 0; fr < 2; fr++)
            #pragma unroll
            for (int q = 0; q < 4; q++) {
                long row = bm + w * 32 + fr * 16 + (l >> 4) * 4 + q;
                atomicAdd(Y + row * 10 + (l & 15), yacc[fr][q]);
            }
    }
}

extern "C" void kernel_launch(void* const* d_in, const int* in_sizes, int n_in,
                              void* d_out, int out_size, void* d_ws, size_t ws_size,
                              hipStream_t stream) {
    const float* x   = (const float*)d_in[0];
    const float* mu1 = (const float*)d_in[1];
    const float* p1  = (const float*)d_in[2];
    const float* e1  = (const float*)d_in[3];
    const float* mu2 = (const float*)d_in[4];
    const float* p2  = (const float*)d_in[5];
    const float* e2  = (const float*)d_in[6];
    const float* mu3 = (const float*)d_in[7];
    const float* p3  = (const float*)d_in[8];
    const float* e3  = (const float*)d_in[9];
    float* out = (float*)d_out;

    const int B = 65536, D = 512, DO = 10;

    char* ws = (char*)d_ws;
    bf16* Wt1 = (bf16*)(ws);
    bf16* Wt2 = (bf16*)(ws + 524288);
    bf16* Wt3 = (bf16*)(ws + 1048576);
    bf16* xb  = (bf16*)(ws + 1114112);
    bf16* h1  = (bf16*)(ws + 1114112 + 67108864);

    float* osc = out + (long)B * DO;

    hipLaunchKernelGGL(k_zero, dim3(512), dim3(256), 0, stream, out, out_size);
    hipLaunchKernelGGL(k_prep_all, dim3(528), dim3(256), 0, stream,
                       mu1, p1, e1, mu2, p2, e2, mu3, p3, e3, Wt1, Wt2, Wt3, osc);
    hipLaunchKernelGGL(k_cvt, dim3(2048), dim3(256), 0, stream,
                       (const float4*)x, (bf16x4*)xb, B * D / 4);
    hipLaunchKernelGGL(k_g1, dim3(512), dim3(512), 0, stream, xb, Wt1, h1);
    hipLaunchKernelGGL(k_g2, dim3(512), dim3(512), 0, stream, h1, Wt2, Wt3, out);
}

// Round 8
// 190.804 us; speedup vs baseline: 1.3420x; 1.0308x over previous
//
#include <hip/hip_runtime.h>
#include <hip/hip_bf16.h>
#include <stdint.h>

typedef __bf16 bf16;
typedef bf16 bf16x8 __attribute__((ext_vector_type(8)));
typedef float f32x4 __attribute__((ext_vector_type(4)));

#define LOGSQRT2PI 0.9189385332046727f
#define SB0() __builtin_amdgcn_sched_barrier(0)

__device__ __forceinline__ void gload_lds16(const void* g, void* l) {
    __builtin_amdgcn_global_load_lds((__attribute__((address_space(1))) void*)g,
                                     (__attribute__((address_space(3))) void*)l,
                                     16, 0, 0);
}

// ---- merged weight prep (verbatim round-6, passing): W = mu+(1e-6+softplus(p))*eps;
// ---- Wt[n][k] bf16; lqw/lpw atomics. Blocks 0-255 W1, 256-511 W2, 512-527 W3.
__device__ __forceinline__ void prep_body(const float* __restrict__ mu,
        const float* __restrict__ p, const float* __restrict__ eps,
        bf16* __restrict__ Wt, int N, int Npad, float* __restrict__ osc,
        int vb, int nblocks) {
    int total = 512 * Npad;
    float lqw = 0.f, lpw = 0.f;
    for (int idx = vb * 256 + threadIdx.x; idx < total; idx += nblocks * 256) {
        int k = idx / Npad, n = idx - k * Npad;
        float w = 0.f;
        if (n < N) {
            int src = k * N + n;
            float m = mu[src], e = eps[src];
            float sd = 1e-6f + log1pf(expf(p[src]));
            w = m + sd * e;
            float z = (w - m) / sd;
            lqw += -LOGSQRT2PI - logf(sd) - 0.5f * z * z;
            lpw += -LOGSQRT2PI - 0.5f * w * w;
        }
        Wt[n * 512 + k] = (bf16)w;
    }
    #pragma unroll
    for (int off = 32; off; off >>= 1) {
        lqw += __shfl_down(lqw, off);
        lpw += __shfl_down(lpw, off);
    }
    if ((threadIdx.x & 63) == 0) {
        atomicAdd(&osc[0], lqw);
        atomicAdd(&osc[1], lpw);
    }
}

__global__ void k_prep_all(const float* __restrict__ mu1, const float* __restrict__ p1,
                           const float* __restrict__ e1,
                           const float* __restrict__ mu2, const float* __restrict__ p2,
                           const float* __restrict__ e2,
                           const float* __restrict__ mu3, const float* __restrict__ p3,
                           const float* __restrict__ e3,
                           bf16* __restrict__ Wt1, bf16* __restrict__ Wt2,
                           bf16* __restrict__ Wt3, float* __restrict__ osc) {
    int b = blockIdx.x;
    if (b < 256)      prep_body(mu1, p1, e1, Wt1, 512, 512, osc, b, 256);
    else if (b < 512) prep_body(mu2, p2, e2, Wt2, 512, 512, osc, b - 256, 256);
    else              prep_body(mu3, p3, e3, Wt3, 10,  16,  osc, b - 512, 16);
}

// ============================================================================
// Fused 3-layer kernel.  Block = 4 waves x 32 rows = 128 rows; grid 512 = 2
// drifting blocks/CU.  h1 (32 rows x 512) lives in registers as 32 MFMA-A
// fragments (128 VGPR).  Weights triple-buffered in LDS via global_load_lds;
// NO mid-loop vmcnt(0):
//   layer 1: per phase [STAGE(kt+2)] SB0 [cvt uses A(kt) -> compiler waitcnt
//     transitively retires the OLDER stage(kt+1) PRE-barrier (sound cross-wave:
//     each wave proves its own stages before the barrier)] [reload A(kt+1)]
//     [8 bfr + 16 MFMA] [s_barrier].
//   layer 2: counted vmcnt(1) (kt<=13) / vmcnt(0) (kt==14) pre-barrier.
// Transpose scratch scrT (per-wave 4KB, 32x64, 16B-chunk XOR swizzle
//   phys = row*64 + (((col>>3)^(row&7))<<3) + (col&7)): write 2-way max,
//   b128 frag reads exactly at the 8-cycle b128 floor (verified by bank calc).
// Layer-1 tiles 128 cols (acc 64 regs, dies before h1f completes -> peak
//   ~200 VGPR); layer-2 tiles 64 cols (acc 32); layer-3 fused via scrT,
//   y stored directly (full K per block, no atomics, no zeroing of y).
// ============================================================================
__global__ __launch_bounds__(256, 2)
void k_fused(const float* __restrict__ X, const bf16* __restrict__ W1t,
             const bf16* __restrict__ W2t, const bf16* __restrict__ W3t,
             float* __restrict__ Y) {
    __shared__ __align__(16) bf16 LDSe[12288 + 4 * 2048];  // 24KB B(3-buf) + 4x4KB scrT
    const int tid = threadIdx.x;
    const int l = tid & 63, w = tid >> 6;
    const int r = l & 15, kq = l >> 4;
    const int l8 = l * 8;
    const long bm = (long)blockIdx.x * 128;
    bf16* scrT = &LDSe[12288 + w * 2048];

    #define STAGE1(NT, KT, BUF) do {                                           \
        _Pragma("unroll")                                                      \
        for (int s2 = 0; s2 < 2; s2++) {                                       \
            const int c = w * 2 + s2;                                          \
            gload_lds16(W1t + ((NT) * 128 + c * 16 + r) * 512 + (KT) * 32 + kq * 8, \
                        &LDSe[(BUF) * 4096 + c * 512 + l8]);                   \
        } } while (0)
    #define STAGE2(NT2, KT, BUF)                                               \
        gload_lds16(W2t + ((NT2) * 64 + w * 16 + r) * 512 + (KT) * 32 + kq * 8,\
                    &LDSe[(BUF) * 2048 + w * 512 + l8])
    #define MFMA(A, B, C) __builtin_amdgcn_mfma_f32_16x16x32_bf16(A, B, C, 0, 0, 0)

    const float* xw0 = X + (bm + w * 32 + r) * 512 + kq * 8;
    const float* xw1 = xw0 + 16 * 512;

    bf16x8 h1fA[16], h1fB[16];
    f32x4 yacc0 = (f32x4){0.f, 0.f, 0.f, 0.f};
    f32x4 yacc1 = (f32x4){0.f, 0.f, 0.f, 0.f};

    // ================= layer 1: h1f = relu(x @ W1) =================
    #pragma unroll
    for (int nt = 0; nt < 4; nt++) {
        f32x4 acc[2][8];
        #pragma unroll
        for (int i = 0; i < 2; i++)
            #pragma unroll
            for (int j = 0; j < 8; j++) acc[i][j] = (f32x4){0.f, 0.f, 0.f, 0.f};

        STAGE1(nt, 0, 0);
        STAGE1(nt, 1, 1);
        SB0();                              // pin: stages BEFORE A-loads in VM queue
        f32x4 an0 = *(const f32x4*)(xw0);
        f32x4 an1 = *(const f32x4*)(xw0 + 4);
        f32x4 an2 = *(const f32x4*)(xw1);
        f32x4 an3 = *(const f32x4*)(xw1 + 4);
        SB0();
        asm volatile("s_waitcnt vmcnt(6)" ::: "memory");  // st0 retired (8 out - 2)
        __builtin_amdgcn_s_barrier();

        int bR = 0, bS = 2;
        for (int kt = 0; kt < 16; kt++) {
            if (kt < 14) STAGE1(nt, kt + 2, bS);
            SB0();                          // pin: stage(kt+2) before A(kt+1) loads
            bf16x8 afr0, afr1;
            #pragma unroll
            for (int e = 0; e < 4; e++) {   // waits A(kt) -> retires stage(kt+1)
                afr0[e] = (bf16)an0[e]; afr0[e + 4] = (bf16)an1[e];
                afr1[e] = (bf16)an2[e]; afr1[e + 4] = (bf16)an3[e];
            }
            if (kt < 15) {
                an0 = *(const f32x4*)(xw0 + (kt + 1) * 32);
                an1 = *(const f32x4*)(xw0 + (kt + 1) * 32 + 4);
                an2 = *(const f32x4*)(xw1 + (kt + 1) * 32);
                an3 = *(const f32x4*)(xw1 + (kt + 1) * 32 + 4);
            }
            #pragma unroll
            for (int j = 0; j < 8; j++) {
                bf16x8 bfr = *(const bf16x8*)&LDSe[bR * 4096 + j * 512 + l8];
                acc[0][j] = MFMA(afr0, bfr, acc[0][j]);
                acc[1][j] = MFMA(afr1, bfr, acc[1][j]);
            }
            __builtin_amdgcn_s_barrier();
            bR = (bR == 2) ? 0 : bR + 1;
            bS = (bS == 2) ? 0 : bS + 1;
        }

        // transpose (wave-private) in two 64-col halves -> h1f registers
        #pragma unroll
        for (int h = 0; h < 2; h++) {
            #pragma unroll
            for (int rh = 0; rh < 2; rh++)
                #pragma unroll
                for (int jh = 0; jh < 4; jh++)
                    #pragma unroll
                    for (int q = 0; q < 4; q++) {
                        int row = rh * 16 + kq * 4 + q;
                        int col = jh * 16 + r;
                        float v = fmaxf(acc[rh][h * 4 + jh][q], 0.f);
                        scrT[row * 64 + (((col >> 3) ^ (row & 7)) << 3) + (col & 7)] = (bf16)v;
                    }
            asm volatile("s_waitcnt lgkmcnt(0)" ::: "memory");
            SB0();
            #pragma unroll
            for (int ktl = 0; ktl < 2; ktl++) {
                h1fA[nt * 4 + h * 2 + ktl] = *(const bf16x8*)
                    &scrT[r * 64 + (((ktl * 4 + kq) ^ (r & 7)) << 3)];
                h1fB[nt * 4 + h * 2 + ktl] = *(const bf16x8*)
                    &scrT[(16 + r) * 64 + (((ktl * 4 + kq) ^ (r & 7)) << 3)];
            }
            asm volatile("s_waitcnt lgkmcnt(0)" ::: "memory");  // reads before overwrite
            SB0();
        }
    }

    // ============ layers 2+3: h2 = relu(h1 @ W2); y += h2 @ W3 ============
    #pragma unroll 1
    for (int nt2 = 0; nt2 < 8; nt2++) {
        f32x4 acc2[2][4];
        #pragma unroll
        for (int i = 0; i < 2; i++)
            #pragma unroll
            for (int j = 0; j < 4; j++) acc2[i][j] = (f32x4){0.f, 0.f, 0.f, 0.f};

        STAGE2(nt2, 0, 0);
        STAGE2(nt2, 1, 1);
        asm volatile("s_waitcnt vmcnt(1)" ::: "memory");
        __builtin_amdgcn_s_barrier();

        #pragma unroll
        for (int kt = 0; kt < 16; kt++) {
            const int bR2 = kt % 3;                      // static (unrolled)
            if (kt < 14) STAGE2(nt2, kt + 2, (kt + 2) % 3);
            #pragma unroll
            for (int j = 0; j < 4; j++) {
                bf16x8 bfr = *(const bf16x8*)&LDSe[bR2 * 2048 + j * 512 + l8];
                acc2[0][j] = MFMA(h1fA[kt], bfr, acc2[0][j]);
                acc2[1][j] = MFMA(h1fB[kt], bfr, acc2[1][j]);
            }
            if (kt <= 13)      { asm volatile("s_waitcnt vmcnt(1)" ::: "memory"); }
            else if (kt == 14) { asm volatile("s_waitcnt vmcnt(0)" ::: "memory"); }
            __builtin_amdgcn_s_barrier();
        }

        // h2 tile -> scrT (ReLU) -> layer-3 partial into yacc
        #pragma unroll
        for (int rh = 0; rh < 2; rh++)
            #pragma unroll
            for (int j = 0; j < 4; j++)
                #pragma unroll
                for (int q = 0; q < 4; q++) {
                    int row = rh * 16 + kq * 4 + q;
                    int col = j * 16 + r;
                    float v = fmaxf(acc2[rh][j][q], 0.f);
                    scrT[row * 64 + (((col >> 3) ^ (row & 7)) << 3) + (col & 7)] = (bf16)v;
                }
        asm volatile("s_waitcnt lgkmcnt(0)" ::: "memory");
        SB0();
        #pragma unroll
        for (int ktl = 0; ktl < 2; ktl++) {
            bf16x8 w3 = *(const bf16x8*)(W3t + r * 512 + nt2 * 64 + ktl * 32 + kq * 8);
            bf16x8 aA = *(const bf16x8*)&scrT[r * 64 + (((ktl * 4 + kq) ^ (r & 7)) << 3)];
            bf16x8 aB = *(const bf16x8*)&scrT[(16 + r) * 64 + (((ktl * 4 + kq) ^ (r & 7)) << 3)];
            yacc0 = MFMA(aA, w3, yacc0);
            yacc1 = MFMA(aB, w3, yacc1);
        }
        asm volatile("s_waitcnt lgkmcnt(0)" ::: "memory");  // before next nt2 overwrites
        SB0();
    }

    // y store: col = r (<10), rows = wave's 32 rows
    if (r < 10) {
        #pragma unroll
        for (int q = 0; q < 4; q++) {
            Y[(bm + w * 32 + kq * 4 + q) * 10 + r]      = yacc0[q];
            Y[(bm + w * 32 + 16 + kq * 4 + q) * 10 + r] = yacc1[q];
        }
    }
    #undef STAGE1
    #undef STAGE2
    #undef MFMA
}

extern "C" void kernel_launch(void* const* d_in, const int* in_sizes, int n_in,
                              void* d_out, int out_size, void* d_ws, size_t ws_size,
                              hipStream_t stream) {
    const float* x   = (const float*)d_in[0];
    const float* mu1 = (const float*)d_in[1];
    const float* p1  = (const float*)d_in[2];
    const float* e1  = (const float*)d_in[3];
    const float* mu2 = (const float*)d_in[4];
    const float* p2  = (const float*)d_in[5];
    const float* e2  = (const float*)d_in[6];
    const float* mu3 = (const float*)d_in[7];
    const float* p3  = (const float*)d_in[8];
    const float* e3  = (const float*)d_in[9];
    float* out = (float*)d_out;

    const int B = 65536, DO = 10;

    char* ws = (char*)d_ws;
    bf16* Wt1 = (bf16*)(ws);
    bf16* Wt2 = (bf16*)(ws + 524288);
    bf16* Wt3 = (bf16*)(ws + 1048576);

    float* osc = out + (long)B * DO;

    hipMemsetAsync(osc, 0, 2 * sizeof(float), stream);
    hipLaunchKernelGGL(k_prep_all, dim3(528), dim3(256), 0, stream,
                       mu1, p1, e1, mu2, p2, e2, mu3, p3, e3, Wt1, Wt2, Wt3, osc);
    hipLaunchKernelGGL(k_fused, dim3(512), dim3(256), 0, stream,
                       x, Wt1, Wt2, Wt3, out);
}